// Round 8
// baseline (378.541 us; speedup 1.0000x reference)
//
#include <hip/hip_runtime.h>
#include <math.h>

typedef __bf16 bf16x8 __attribute__((ext_vector_type(8)));
typedef float  f32x4  __attribute__((ext_vector_type(4)));
typedef unsigned short u16x8 __attribute__((ext_vector_type(8)));

#define NEGF (-1e20f)

__device__ __forceinline__ unsigned short f2bf(float f) {
  union { float f; unsigned u; } x; x.f = f;
  unsigned r = x.u + 0x7fffu + ((x.u >> 16) & 1u);
  return (unsigned short)(r >> 16);
}
__device__ __forceinline__ unsigned short f2bfh(float f) {
  __bf16 h = (__bf16)f;
  return __builtin_bit_cast(unsigned short, h);
}
__device__ __forceinline__ float bf2f(unsigned short h) {
  union { unsigned u; float f; } x; x.u = ((unsigned)h) << 16;
  return x.f;
}

__device__ __forceinline__ void gl16(const void* g, void* l) {
  __builtin_amdgcn_global_load_lds(
      (const __attribute__((address_space(1))) unsigned int*)g,
      (__attribute__((address_space(3))) unsigned int*)l, 16, 0, 0);
}
__device__ __forceinline__ unsigned lds_addr(const void* p) {
  return (unsigned)(unsigned long long)(const __attribute__((address_space(3))) char*)p;
}

#define DSR(dst, off) asm volatile("ds_read_b128 %0, %1" : "=v"(dst) : "v"(off))
#define LGKM0 asm volatile("s_waitcnt lgkmcnt(0)" ::: "memory")
#define VMC0  asm volatile("s_waitcnt vmcnt(0)" ::: "memory")
#define SBAR  __builtin_amdgcn_s_barrier()
#define SCH0  __builtin_amdgcn_sched_barrier(0)

// ---------------- W (1024x1024 f32) -> W^T bf16, 3 weights ------------
__global__ __launch_bounds__(256) void k_cvt_w3(
    const float* __restrict__ Wq, const float* __restrict__ Wk, const float* __restrict__ Wv,
    unsigned short* __restrict__ Tq, unsigned short* __restrict__ Tk, unsigned short* __restrict__ Tv) {
  const float* W = (blockIdx.z == 0) ? Wq : (blockIdx.z == 1) ? Wk : Wv;
  unsigned short* WT = (blockIdx.z == 0) ? Tq : (blockIdx.z == 1) ? Tk : Tv;
  __shared__ float t[32][33];
  const int tid = threadIdx.x;
  const int tx = tid & 31, ty = tid >> 5;
  const int e0 = blockIdx.y * 32, a0 = blockIdx.x * 32;
#pragma unroll
  for (int i = 0; i < 4; i++) {
    int el = ty + i * 8;
    t[el][tx] = W[(size_t)(e0 + el) * 1024 + a0 + tx];
  }
  __syncthreads();
#pragma unroll
  for (int i = 0; i < 4; i++) {
    int al = ty + i * 8;
    WT[(size_t)(a0 + al) * 1024 + e0 + tx] = f2bf(t[tx][al]);
  }
}

// ---------------- mask int32 -> bits, grid-stride ---------------------
__global__ __launch_bounds__(256) void k_maskbits(const int* __restrict__ mask,
                                                  unsigned short* __restrict__ bits) {
#pragma unroll
  for (int it = 0; it < 4; it++) {
    size_t t = (size_t)it * 524288 + (size_t)blockIdx.x * 256 + threadIdx.x;
    const int4* p = (const int4*)(mask + t * 16);
    int4 a = p[0], b = p[1], c = p[2], d = p[3];
    unsigned m = 0;
    m |= (a.x != 0) ? 1u : 0u;      m |= (a.y != 0) ? 2u : 0u;
    m |= (a.z != 0) ? 4u : 0u;      m |= (a.w != 0) ? 8u : 0u;
    m |= (b.x != 0) ? 16u : 0u;     m |= (b.y != 0) ? 32u : 0u;
    m |= (b.z != 0) ? 64u : 0u;     m |= (b.w != 0) ? 128u : 0u;
    m |= (c.x != 0) ? 256u : 0u;    m |= (c.y != 0) ? 512u : 0u;
    m |= (c.z != 0) ? 1024u : 0u;   m |= (c.w != 0) ? 2048u : 0u;
    m |= (d.x != 0) ? 4096u : 0u;   m |= (d.y != 0) ? 8192u : 0u;
    m |= (d.z != 0) ? 16384u : 0u;  m |= (d.w != 0) ? 32768u : 0u;
    bits[t] = (unsigned short)m;
  }
}

// =====================================================================
// 256x256 projection with FUSED f32->bf16 on the big operand.
// FSIDE 0: A (rows=brow) is f32   [qp, kp]
// FSIDE 1: B (rows=bcol) is f32   [vpT]
// f32 side: reg-staged (8x float4) -> hw cvt -> swizzled ds_write_b128.
// bf16 side (W^T): global_load_lds. 2-phase pipeline, BK=64, 8 waves.
// =====================================================================
template<int FSIDE>
__global__ __launch_bounds__(512, 2) void k_proj256(
    const float* __restrict__ F, int ldf,
    const unsigned short* __restrict__ H, int ldh,
    unsigned short* __restrict__ C, int ldc, float scale)
{
  const int nwg = gridDim.x * gridDim.y;
  int lin = blockIdx.y * gridDim.x + blockIdx.x;
  int swz = (lin & 7) * (nwg >> 3) + (lin >> 3);   // nwg % 8 == 0
  const int bx = swz % gridDim.x, by = swz / gridDim.x;
  const int brow = by * 256, bcol = bx * 256;

  __shared__ unsigned short As[2][256 * 64];
  __shared__ unsigned short Bs[2][256 * 64];

  const int tid = threadIdx.x, w = tid >> 6, l = tid & 63;
  const int wr = w >> 2, wc = w & 3;
  const int fr = l & 15, fq = l >> 4;

  // f32-side staging map: 4 rows x 1 chunk per thread
  const int sr4 = tid >> 3;        // 0..63 -> rows sr4*4+i
  const int scn = tid & 7;         // 16B chunk
  // bf16-side gl16 map
  const int hr = l >> 3;
  const int hc = ((l & 7) ^ hr) * 8;

  const int fbase = (FSIDE == 0) ? brow : bcol;
  const int hbase = (FSIDE == 0) ? bcol : brow;
  const float* gF = F + (size_t)(fbase + sr4 * 4) * ldf + scn * 8;
  const unsigned short* gH = H + (size_t)(hbase + w * 32 + hr) * ldh + hc;

  unsigned short* Fl = (FSIDE == 0) ? &As[0][0] : &Bs[0][0];
  unsigned short* Hl = (FSIDE == 0) ? &Bs[0][0] : &As[0][0];

  f32x4 acc[8][4] = {};

  unsigned aA[8], aB[4];
#pragma unroll
  for (int m = 0; m < 8; m++) aA[m] = lds_addr(&As[0][0]) + (unsigned)((wr * 128 + m * 16 + fr) * 128);
#pragma unroll
  for (int n = 0; n < 4; n++) aB[n] = lds_addr(&Bs[0][0]) + (unsigned)((wc * 64 + n * 16 + fr) * 128);
  const unsigned ck0 = (unsigned)((fq ^ (fr & 7)) * 16);
  const unsigned ck1 = (unsigned)(((4 + fq) ^ (fr & 7)) * 16);

  float4 fa[8];
  auto loadF = [&](int k0) {
#pragma unroll
    for (int i = 0; i < 4; i++) {
      const float* p = gF + (size_t)i * ldf + k0;
      fa[2 * i]     = *(const float4*)p;
      fa[2 * i + 1] = *(const float4*)(p + 4);
    }
  };
  auto writeF = [&](int buf) {
    unsigned short* lb = Fl + buf * (256 * 64);
#pragma unroll
    for (int i = 0; i < 4; i++) {
      int row = sr4 * 4 + i;
      u16x8 o;
      o[0] = f2bfh(fa[2 * i].x);     o[1] = f2bfh(fa[2 * i].y);
      o[2] = f2bfh(fa[2 * i].z);     o[3] = f2bfh(fa[2 * i].w);
      o[4] = f2bfh(fa[2 * i + 1].x); o[5] = f2bfh(fa[2 * i + 1].y);
      o[6] = f2bfh(fa[2 * i + 1].z); o[7] = f2bfh(fa[2 * i + 1].w);
      *(u16x8*)&lb[row * 64 + ((scn ^ (row & 7)) * 8)] = o;
    }
  };
  auto stageH = [&](int buf, int k0) {
    unsigned short* lb = Hl + buf * (256 * 64);
#pragma unroll
    for (int i = 0; i < 4; i++)
      gl16(gH + (size_t)(8 * i) * ldh + k0, lb + (w * 32 + 8 * i) * 64);
  };

  const int NT = 16;   // K = 1024, BK = 64
  loadF(0); stageH(0, 0);
  VMC0;
  writeF(0);
  LGKM0; SBAR;

  for (int t = 0; t < NT; ++t) {
    if (t + 1 < NT) { loadF((t + 1) << 6); stageH((t + 1) & 1, (t + 1) << 6); SCH0; }
    const unsigned bo = (unsigned)((t & 1) * (256 * 64 * 2));
    u16x8 ar[8], br[4];
#pragma unroll
    for (int m = 0; m < 8; m++) DSR(ar[m], aA[m] + bo + ck0);
#pragma unroll
    for (int n = 0; n < 4; n++) DSR(br[n], aB[n] + bo + ck0);
    LGKM0; SCH0;
    __builtin_amdgcn_s_setprio(1);
#pragma unroll
    for (int m = 0; m < 8; m++)
#pragma unroll
      for (int n = 0; n < 4; n++)
        acc[m][n] = __builtin_amdgcn_mfma_f32_16x16x32_bf16(
            __builtin_bit_cast(bf16x8, ar[m]), __builtin_bit_cast(bf16x8, br[n]), acc[m][n], 0, 0, 0);
    __builtin_amdgcn_s_setprio(0);
    u16x8 ar2[8], br2[4];
#pragma unroll
    for (int m = 0; m < 8; m++) DSR(ar2[m], aA[m] + bo + ck1);
#pragma unroll
    for (int n = 0; n < 4; n++) DSR(br2[n], aB[n] + bo + ck1);
    LGKM0; SCH0;
    __builtin_amdgcn_s_setprio(1);
#pragma unroll
    for (int m = 0; m < 8; m++)
#pragma unroll
      for (int n = 0; n < 4; n++)
        acc[m][n] = __builtin_amdgcn_mfma_f32_16x16x32_bf16(
            __builtin_bit_cast(bf16x8, ar2[m]), __builtin_bit_cast(bf16x8, br2[n]), acc[m][n], 0, 0, 0);
    __builtin_amdgcn_s_setprio(0);
    SCH0;
    VMC0;
    if (t + 1 < NT) writeF((t + 1) & 1);
    LGKM0; SBAR;
  }

#pragma unroll
  for (int m = 0; m < 8; m++)
#pragma unroll
    for (int n = 0; n < 4; n++)
#pragma unroll
      for (int r = 0; r < 4; r++) {
        int rg = brow + wr * 128 + m * 16 + fq * 4 + r;
        int cg = bcol + wc * 64 + n * 16 + fr;
        C[(size_t)rg * ldc + cg] = f2bf(acc[m][n][r] * scale);
      }
}

// =====================================================================
// minimum-2-phase core, 128x128 tile, BK=64, 4 waves (unchanged r7 core)
// =====================================================================
__device__ __forceinline__ void tile128_gemm(
    const unsigned short* __restrict__ A, int lda,
    const unsigned short* __restrict__ Bt, int ldb,
    int brow, int bcol, int NT,
    unsigned short* AsBase, unsigned short* BsBase,
    int wr, int wc, int fr, int fq,
    f32x4 (&acc)[4][4])
{
  const int tid = threadIdx.x, wid = tid >> 6, l = tid & 63;
  const int sr = l >> 3;
  const int sc = ((l & 7) ^ sr) * 8;

  const unsigned short* ga = A + (size_t)(brow + wid * 32 + sr) * lda + sc;
  const unsigned short* gb = Bt + (size_t)(bcol + wid * 32 + sr) * ldb + sc;

  unsigned aA[4], aB[4];
#pragma unroll
  for (int m = 0; m < 4; m++) aA[m] = lds_addr(AsBase) + (unsigned)((wr * 64 + m * 16 + fr) * 128);
#pragma unroll
  for (int n = 0; n < 4; n++) aB[n] = lds_addr(BsBase) + (unsigned)((wc * 64 + n * 16 + fr) * 128);
  const unsigned ck0 = (unsigned)((fq ^ (fr & 7)) * 16);
  const unsigned ck1 = (unsigned)(((4 + fq) ^ (fr & 7)) * 16);

  auto stage = [&](int buf, int k0) {
    unsigned short* la = AsBase + buf * (128 * 64);
    unsigned short* lb = BsBase + buf * (128 * 64);
#pragma unroll
    for (int i = 0; i < 4; i++) {
      gl16(ga + (size_t)(8 * i) * lda + k0, la + (wid * 32 + 8 * i) * 64);
      gl16(gb + (size_t)(8 * i) * ldb + k0, lb + (wid * 32 + 8 * i) * 64);
    }
  };

  stage(0, 0);
  VMC0; SBAR;

  for (int t = 0; t < NT; ++t) {
    if (t + 1 < NT) stage((t + 1) & 1, (t + 1) << 6);
    const unsigned bo = (unsigned)((t & 1) * (128 * 64 * 2));
    u16x8 ar[4], br[4];
#pragma unroll
    for (int m = 0; m < 4; m++) DSR(ar[m], aA[m] + bo + ck0);
#pragma unroll
    for (int n = 0; n < 4; n++) DSR(br[n], aB[n] + bo + ck0);
    LGKM0; SCH0;
    __builtin_amdgcn_s_setprio(1);
#pragma unroll
    for (int m = 0; m < 4; m++)
#pragma unroll
      for (int n = 0; n < 4; n++)
        acc[m][n] = __builtin_amdgcn_mfma_f32_16x16x32_bf16(
            __builtin_bit_cast(bf16x8, ar[m]), __builtin_bit_cast(bf16x8, br[n]), acc[m][n], 0, 0, 0);
    __builtin_amdgcn_s_setprio(0);
    u16x8 ar2[4], br2[4];
#pragma unroll
    for (int m = 0; m < 4; m++) DSR(ar2[m], aA[m] + bo + ck1);
#pragma unroll
    for (int n = 0; n < 4; n++) DSR(br2[n], aB[n] + bo + ck1);
    LGKM0; SCH0;
    __builtin_amdgcn_s_setprio(1);
#pragma unroll
    for (int m = 0; m < 4; m++)
#pragma unroll
      for (int n = 0; n < 4; n++)
        acc[m][n] = __builtin_amdgcn_mfma_f32_16x16x32_bf16(
            __builtin_bit_cast(bf16x8, ar2[m]), __builtin_bit_cast(bf16x8, br2[n]), acc[m][n], 0, 0, 0);
    __builtin_amdgcn_s_setprio(0);
    SCH0;
    VMC0;
    SBAR;
  }
}

// ---------------- scores: 128-tile causal grid + packed mask, bf16 out -
__global__ __launch_bounds__(256, 2) void k_scores(
    const unsigned short* __restrict__ QP,
    const unsigned short* __restrict__ KP,
    unsigned short* __restrict__ S,
    const unsigned short* __restrict__ maskbits)
{
  int bid0 = blockIdx.x;
  int bid = (bid0 & 7) * 136 + (bid0 >> 3);   // 1088 % 8 == 0: bijective
  const int b = bid / 136;
  int t0 = bid - b * 136;
  int by = (int)((sqrtf((float)(8 * t0 + 1)) - 1.0f) * 0.5f);
  if ((by + 1) * (by + 2) / 2 <= t0) by++;
  else if (by * (by + 1) / 2 > t0) by--;
  const int bx = t0 - (by * (by + 1)) / 2;     // bx <= by
  const int brow = by * 128, bcol = bx * 128;

  const unsigned short* A  = QP + (size_t)b * (2048 * 1024);
  const unsigned short* Bt = KP + (size_t)b * (2048 * 1024);

  __shared__ unsigned short As[2][128 * 64];
  __shared__ unsigned short Bs[2][128 * 64];

  const int tid = threadIdx.x, wid = tid >> 6, lane = tid & 63;
  const int wr = wid >> 1, wc = wid & 1;
  const int fr = lane & 15, fq = lane >> 4;

  const unsigned short* bits = maskbits + (size_t)b * 2048 * 128;
  unsigned mbits[2] = {0u, 0u};
#pragma unroll
  for (int m = 0; m < 4; m++)
#pragma unroll
    for (int r = 0; r < 4; r++) {
      int qq = brow + wr * 64 + m * 16 + fq * 4 + r;
      unsigned long long mw =
          *(const unsigned long long*)(bits + (size_t)qq * 128 + ((bcol + wc * 64) >> 4));
#pragma unroll
      for (int n = 0; n < 4; n++) {
        int jj = (m << 4) | (n << 2) | r;
        unsigned bit = (unsigned)((mw >> (n * 16 + fr)) & 1ull);
        mbits[jj >> 5] |= bit << (jj & 31);
      }
    }
  asm volatile("" ::: "memory");

  f32x4 acc[4][4] = {};
  tile128_gemm(A, 1024, Bt, 1024, brow, bcol, 16, &As[0][0], &Bs[0][0],
               wr, wc, fr, fq, acc);

  unsigned short* Cb = S + (size_t)b * 2048 * 2048;
#pragma unroll
  for (int m = 0; m < 4; m++)
#pragma unroll
    for (int n = 0; n < 4; n++)
#pragma unroll
      for (int r = 0; r < 4; r++) {
        int jj = (m << 4) | (n << 2) | r;
        int qq = brow + wr * 64 + m * 16 + fq * 4 + r;
        int kk = bcol + wc * 64 + n * 16 + fr;
        float s = acc[m][n][r];
        if (!((mbits[jj >> 5] >> (jj & 31)) & 1u)) s = NEGF;
        if (kk > qq) s = NEGF;
        else if (s == 0.0f) s = NEGF;
        Cb[(size_t)qq * 2048 + kk] = f2bf(s);
      }
}

// ---------------- PV (f32 out, K truncated at diagonal) ---------------
__global__ __launch_bounds__(256, 2) void k_pv(
    const unsigned short* __restrict__ P,
    const unsigned short* __restrict__ VpT,
    float* __restrict__ Out)
{
  const int b = blockIdx.z;
  const int by = (int)(gridDim.y - 1 - blockIdx.y);   // long K first
  const int bx = blockIdx.x;
  const int brow = by * 128, bcol = bx * 128;

  const unsigned short* A  = P + (size_t)b * 2048 * 2048;
  const unsigned short* Bt = VpT + (size_t)b * 2048;

  __shared__ unsigned short As[2][128 * 64];
  __shared__ unsigned short Bs[2][128 * 64];

  const int tid = threadIdx.x, wid = tid >> 6, lane = tid & 63;
  const int wr = wid >> 1, wc = wid & 1;
  const int fr = lane & 15, fq = lane >> 4;

  f32x4 acc[4][4] = {};
  const int NT = (brow + 128) >> 6;
  tile128_gemm(A, 2048, Bt, 16384, brow, bcol, NT, &As[0][0], &Bs[0][0],
               wr, wc, fr, fq, acc);

  float* C = Out + (size_t)b * 2048 * 1024;
#pragma unroll
  for (int m = 0; m < 4; m++)
#pragma unroll
    for (int n = 0; n < 4; n++)
#pragma unroll
      for (int r = 0; r < 4; r++) {
        int rg = brow + wr * 64 + m * 16 + fq * 4 + r;
        int cg = bcol + wc * 64 + n * 16 + fr;
        C[(size_t)rg * 1024 + cg] = acc[m][n][r];
      }
}

// ---------------- row softmax, bf16 in/out, vectorized ----------------
__global__ __launch_bounds__(256) void k_softmax_bf(unsigned short* __restrict__ S) {
  const int row = blockIdx.x;
  const int qq = row & 2047;
  const int L = ((qq >> 7) + 1) << 7;
  const int tid = threadIdx.x;
  unsigned short* p = S + (size_t)row * 2048;
  float val[8];
  float mx = -3.0e38f;
  int cnt = 0;
  for (int i = tid; i * 4 < L; i += 256) {
    ushort4 u = *(const ushort4*)(p + i * 4);
    float a = bf2f(u.x), bb = bf2f(u.y), c = bf2f(u.z), d = bf2f(u.w);
    val[cnt] = a; val[cnt + 1] = bb; val[cnt + 2] = c; val[cnt + 3] = d;
    mx = fmaxf(fmaxf(fmaxf(mx, a), bb), fmaxf(c, d));
    cnt += 4;
  }
#pragma unroll
  for (int o = 32; o; o >>= 1) mx = fmaxf(mx, __shfl_xor(mx, o));
  __shared__ float sred[8];
  if ((tid & 63) == 0) sred[tid >> 6] = mx;
  __syncthreads();
  mx = fmaxf(fmaxf(sred[0], sred[1]), fmaxf(sred[2], sred[3]));
  float sum = 0.f;
  for (int j = 0; j < cnt; j++) { val[j] = __expf(val[j] - mx); sum += val[j]; }
#pragma unroll
  for (int o = 32; o; o >>= 1) sum += __shfl_xor(sum, o);
  if ((tid & 63) == 0) sred[4 + (tid >> 6)] = sum;
  __syncthreads();
  sum = (sred[4] + sred[5]) + (sred[6] + sred[7]);
  const float inv = 1.0f / sum;
  int j = 0;
  for (int i = tid; i * 4 < L; i += 256) {
    ushort4 o;
    o.x = f2bf(val[j] * inv);     o.y = f2bf(val[j + 1] * inv);
    o.z = f2bf(val[j + 2] * inv); o.w = f2bf(val[j + 3] * inv);
    *(ushort4*)(p + i * 4) = o;
    j += 4;
  }
}

extern "C" void kernel_launch(void* const* d_in, const int* in_sizes, int n_in,
                              void* d_out, int out_size, void* d_ws, size_t ws_size,
                              hipStream_t stream) {
  const float* q   = (const float*)d_in[0];
  const float* k   = (const float*)d_in[1];
  const float* v   = (const float*)d_in[2];
  const int*   msk = (const int*)d_in[3];
  const float* Wq  = (const float*)d_in[4];
  const float* Wk  = (const float*)d_in[5];
  const float* Wv  = (const float*)d_in[6];
  float* out = (float*)d_out;

  char* ws = (char*)d_ws;
  unsigned short* WqT = (unsigned short*)(ws + 0);
  unsigned short* WkT = (unsigned short*)(ws + 2097152);
  unsigned short* WvT = (unsigned short*)(ws + 4194304);
  unsigned short* qp  = (unsigned short*)(ws + 6291456);
  unsigned short* kp  = (unsigned short*)(ws + 39845888);
  unsigned short* vpT = (unsigned short*)(ws + 73400320);
  unsigned short* P   = (unsigned short*)(ws + 106954752);   // 67 MB bf16 scores
  unsigned short* mbitsbuf = (unsigned short*)(ws + 207618048);  // 4 MiB

  dim3 blk(256), blk5(512);
  // 1) weight transpose + mask packing
  k_cvt_w3<<<dim3(32, 32, 3), blk, 0, stream>>>(Wq, Wk, Wv, WqT, WkT, WvT);
  k_maskbits<<<dim3(2048), blk, 0, stream>>>(msk, mbitsbuf);

  // 2) projections with fused f32->bf16 (no separate cvt pass)
  k_proj256<0><<<dim3(4, 64), blk5, 0, stream>>>(q, 1024, WqT, 1024, qp, 1024, 0.03125f);
  k_proj256<0><<<dim3(4, 64), blk5, 0, stream>>>(k, 1024, WkT, 1024, kp, 1024, 1.0f);
  k_proj256<1><<<dim3(64, 4), blk5, 0, stream>>>(v, 1024, WvT, 1024, vpT, 16384, 1.0f);

  // 3) scores (bf16 out, compact causal grid, packed mask bits)
  k_scores<<<dim3(1088), blk, 0, stream>>>(qp, kp, P, mbitsbuf);

  // 4) softmax in place (bf16)
  k_softmax_bf<<<dim3(16384), blk, 0, stream>>>(P);

  // 5) PV: out = P x vpT^T, K truncated at diagonal (long blocks first)
  k_pv<<<dim3(8, 16, 8), blk, 0, stream>>>(P, vpT, out);
  (void)in_sizes; (void)n_in; (void)out_size; (void)ws_size;
}